// Round 4
// baseline (125.871 us; speedup 1.0000x reference)
//
#include <hip/hip_runtime.h>
#include <hip/hip_bf16.h>
#include <stdint.h>

#define B_N 8192
#define D_N 1024
#define K_N 8
#define H_N 2048

#define BM 320
#define BN 256
#define BK 64
#define NBLK 256
// LDS map (bytes): 2 K-step buffers of (A 40960 + B 32768) = 73728:
//   buf0=0 buf1=73728 (end 147456)
//   ro=147456(1280) pll=148736(2560)  total 151296 (<=163840)
#define ABYTES 40960
#define BUFSZ 73728
#define RO_OFF 147456
#define PLL_OFF 148736
#define GEMM_LDS 151296

typedef unsigned int u32;
typedef unsigned short u16;
typedef __attribute__((ext_vector_type(8))) short short8;
typedef __attribute__((ext_vector_type(4))) float float4v;

struct __align__(8) us4 { u16 x, y, z, w; };

__device__ __forceinline__ u16 f2bf(float f) {
    union { float f; u32 u; } v; v.f = f;
    u32 u = v.u;
    u32 r = (u + 0x7fffu + ((u >> 16) & 1u)) >> 16;
    return (u16)r;
}

__device__ __forceinline__ float fast_tanh(float x) {
    float t = __expf(2.0f * x);
    return 1.0f - 2.0f * __builtin_amdgcn_rcpf(t + 1.0f);
}

__device__ __forceinline__ void async_copy16(void* lds, const void* g) {
    __builtin_amdgcn_global_load_lds(
        (const __attribute__((address_space(1))) void*)g,
        (__attribute__((address_space(3))) void*)lds, 16, 0, 0);
}

// ---------------- routing: f64 argmin + x->bf16 (NO atomics) ----------------
__global__ void route_kernel(const float* __restrict__ x,
                             const float* __restrict__ cent,
                             u16* __restrict__ xbf,
                             int* __restrict__ cluster,
                             u32* __restrict__ counts) {
    int tid = threadIdx.x;
    if (blockIdx.x == 0 && tid < K_N) counts[tid * 32] = 0;  // zero strided counters
    int wave = tid >> 6, lane = tid & 63;
    int b = blockIdx.x * 4 + wave;
    const float* xr = x + (size_t)b * D_N;

    float4 xv[4];
#pragma unroll
    for (int i = 0; i < 4; ++i)
        xv[i] = *(const float4*)(xr + i * 256 + lane * 4);

#pragma unroll
    for (int i = 0; i < 4; ++i) {
        us4 o;
        o.x = f2bf(xv[i].x); o.y = f2bf(xv[i].y);
        o.z = f2bf(xv[i].z); o.w = f2bf(xv[i].w);
        *(us4*)(xbf + (size_t)b * D_N + i * 256 + lane * 4) = o;
    }

    double acc[K_N];
#pragma unroll
    for (int k = 0; k < K_N; ++k) {
        const float* cr = cent + k * D_N;
        double s = 0.0;
#pragma unroll
        for (int i = 0; i < 4; ++i) {
            float4 cv = *(const float4*)(cr + i * 256 + lane * 4);
            double d0 = (double)xv[i].x - (double)cv.x; s += d0 * d0;
            double d1 = (double)xv[i].y - (double)cv.y; s += d1 * d1;
            double d2 = (double)xv[i].z - (double)cv.z; s += d2 * d2;
            double d3 = (double)xv[i].w - (double)cv.w; s += d3 * d3;
        }
        acc[k] = s;
    }
#pragma unroll
    for (int k = 0; k < K_N; ++k) {
        double v = acc[k];
        for (int off = 32; off; off >>= 1) v += __shfl_down(v, off);
        acc[k] = v;
    }
    if (lane == 0) {
        int best = 0; double bv = acc[0];
#pragma unroll
        for (int k = 1; k < K_N; ++k)
            if (acc[k] < bv) { bv = acc[k]; best = k; }
        cluster[b] = best;
    }
}

// ---------------- parallel binning: 32 blocks, ballot-rank + block reserve ----------------
__global__ void scatter_kernel(const int* __restrict__ cluster,
                               u32* __restrict__ counts,
                               u32* __restrict__ idxl) {
    __shared__ u32 wcnt[4][K_N];
    __shared__ u32 gb[K_N];
    int tid = threadIdx.x;
    int b = blockIdx.x * 256 + tid;
    int lane = tid & 63, wid = tid >> 6;
    int cl = cluster[b];
    unsigned long long lower = (1ull << lane) - 1ull;
    u32 rank = 0;
#pragma unroll
    for (int k = 0; k < K_N; ++k) {
        unsigned long long mk = __ballot(cl == k);
        if (k == cl) rank = (u32)__popcll(mk & lower);
        if (lane == 0) wcnt[wid][k] = (u32)__popcll(mk);
    }
    __syncthreads();
    if (tid < K_N) {
        u32 tot = wcnt[0][tid] + wcnt[1][tid] + wcnt[2][tid] + wcnt[3][tid];
        gb[tid] = atomicAdd(&counts[tid * 32], tot);   // reserve range (order-free)
    }
    __syncthreads();
    u32 woff = 0;
    if (wid > 0) woff += wcnt[0][cl];
    if (wid > 1) woff += wcnt[1][cl];
    if (wid > 2) woff += wcnt[2][cl];
    idxl[(size_t)cl * B_N + gb[cl] + woff + rank] = (u32)b;
}

// ---------------- W1[k,d,h] f32 -> W1t[k,h,d] bf16 (vectorized) ----------------
__global__ void w1t_kernel(const float* __restrict__ w1, u16* __restrict__ w1t) {
    __shared__ float ts[64][65];
    int tid = threadIdx.x;
    int h0 = blockIdx.x * 64, d0 = blockIdx.y * 64, k = blockIdx.z;
    const float* src = w1 + ((size_t)k * D_N + d0) * H_N + h0;
#pragma unroll
    for (int i = 0; i < 4; ++i) {
        int q = i * 256 + tid;
        int r = q >> 4, c4 = (q & 15) * 4;          // d-row, h-col4
        float4 v = *(const float4*)(src + (size_t)r * H_N + c4);
        ts[c4 + 0][r] = v.x; ts[c4 + 1][r] = v.y;
        ts[c4 + 2][r] = v.z; ts[c4 + 3][r] = v.w;
    }
    __syncthreads();
    u16* dst = w1t + ((size_t)k * H_N + h0) * D_N + d0;
#pragma unroll
    for (int i = 0; i < 4; ++i) {
        int q = i * 256 + tid;
        int hr = q >> 4, d4 = (q & 15) * 4;         // h-row, d-col4
        us4 o;
        o.x = f2bf(ts[hr][d4 + 0]); o.y = f2bf(ts[hr][d4 + 1]);
        o.z = f2bf(ts[hr][d4 + 2]); o.w = f2bf(ts[hr][d4 + 3]);
        *(us4*)(dst + (size_t)hr * D_N + d4) = o;
    }
}

// ---------------- grouped fused GEMM: 320x256 tile, 4 waves (1/SIMD), fat wave tiles ----
// 256 threads/block, 256 blocks (1/CU), persistent-item loop.
// Wave grid 2(wm)x2(wn): wave tile 160x128, acc[10][8] (320 regs, AGPR side).
// Per K-step/wave: 36 ds_read_b128 vs 320 MFMA -> 8.9 MFMA/read (was 2.9):
// LDS pipe (1730 cy/CU/step) hides under MFMA (3100 cy/SIMD/step).
// ONE barrier per K-step; compiler schedules counted lgkm waits (no manual pins).
__global__ __launch_bounds__(256, 1) void gemm_kernel(
                            const u16* __restrict__ xbf,
                            const u16* __restrict__ w1t,
                            const float* __restrict__ b1,
                            const float* __restrict__ w2,
                            const u32* __restrict__ idxl,
                            const u32* __restrict__ counts,
                            float* __restrict__ llp) {
    extern __shared__ char lds[];
    int tid = threadIdx.x;
    int lane = tid & 63, w = tid >> 6;
    int wm = w >> 1, wn = w & 1;
    int wmbase = wm * 160;
    int l15 = lane & 15, l4 = lane >> 4;

    u32* ro = (u32*)(lds + RO_OFF);
    float* pll = (float*)(lds + PLL_OFF);

    // total work items (uniform across block)
    int ntot = 0;
#pragma unroll
    for (int kk = 0; kk < K_N; ++kk)
        ntot += ((int)counts[kk * 32] + BM - 1) / BM;
    int total = ntot * 8;

    // per-lane fragment base offsets (chunk = (kk*4+l4) ^ (row&7); row&7 == l15&7)
    int swz = l15 & 7;
    u32 aB0 = (u32)((wmbase + l15) * 128 + (((0 + l4) ^ swz) << 4));
    u32 aB1 = (u32)((wmbase + l15) * 128 + (((4 + l4) ^ swz) << 4));
    u32 bB0 = (u32)(ABYTES + (wn * 128 + l15) * 128 + (((0 + l4) ^ swz) << 4));
    u32 bB1 = (u32)(ABYTES + (wn * 128 + l15) * 128 + (((4 + l4) ^ swz) << 4));

    const char* xb = (const char*)xbf;
    const char* wb = (const char*)w1t;

    for (int item = blockIdx.x; item < total; item += NBLK) {
        int tile = item >> 3, nc = item & 7;
        // decode (k, mt) from counts prefix
        int k = 0, mt = 0, nt = 0;
#pragma unroll
        for (int kk = 0; kk < K_N; ++kk) {
            int c = (int)counts[kk * 32];
            int t = (c + BM - 1) / BM;
            if (tile >= nt && tile < nt + t) { k = kk; mt = tile - nt; }
            nt += t;
        }
        int cnt = (int)counts[k * 32];
        int rows = cnt - mt * BM; if (rows > BM) rows = BM;
        int h0 = nc * BN;

#pragma unroll 2
        for (int i = tid; i < BM; i += 256) {
            int m = mt * BM + i;
            int mm = m < cnt ? m : cnt - 1;
            ro[i] = idxl[(size_t)k * B_N + mm] * (u32)(D_N * 2);
        }
        __syncthreads();

        // staging source offsets (pre-swizzled: linear LDS dest + swizzled read)
        u32 srcA[10], srcB[8];
#pragma unroll
        for (int i = 0; i < 10; ++i) {
            int c = i * 256 + tid; int r = c >> 3, j = c & 7;
            srcA[i] = ro[r] + ((u32)(j ^ (r & 7)) << 4);
        }
#pragma unroll
        for (int i = 0; i < 8; ++i) {
            int c = i * 256 + tid; int r = c >> 3, j = c & 7;
            srcB[i] = ((u32)(k * H_N + h0 + r) << 11) + ((u32)(j ^ (r & 7)) << 4);
        }

        float4v acc[10][8];
#pragma unroll
        for (int mf = 0; mf < 10; ++mf)
#pragma unroll
            for (int nf = 0; nf < 8; ++nf)
                acc[mf][nf] = (float4v){0.f, 0.f, 0.f, 0.f};

        // prologue: stage K-step 0 into buf 0
        {
            char* Bp = lds;
#pragma unroll
            for (int i = 0; i < 10; ++i)
                async_copy16(Bp + i * 4096 + tid * 16, xb + srcA[i]);
#pragma unroll
            for (int i = 0; i < 8; ++i)
                async_copy16(Bp + ABYTES + i * 4096 + tid * 16, wb + srcB[i]);
        }
        __syncthreads();   // drains vmcnt(0): step-0 data landed

        for (int t = 0; t < 16; ++t) {
            const char* Acur = lds + (t & 1) * BUFSZ;
            char* Bnx = lds + ((t + 1) & 1) * BUFSZ;
            u32 d = (u32)((t + 1) << 7);
            bool pre = (t < 15);
            short8 a0[10], a1[10], c0[8], c1[8];

            // reads for both kk halves; stage ops for t+1 interleaved after kk0 reads
#pragma unroll
            for (int nf = 0; nf < 8; ++nf)
                c0[nf] = *(const short8*)(Acur + bB0 + nf * 2048);
#pragma unroll
            for (int mf = 0; mf < 10; ++mf)
                a0[mf] = *(const short8*)(Acur + aB0 + mf * 2048);
            if (pre) {
#pragma unroll
                for (int i = 0; i < 10; ++i)
                    async_copy16(Bnx + i * 4096 + tid * 16, xb + srcA[i] + d);
#pragma unroll
                for (int i = 0; i < 8; ++i)
                    async_copy16(Bnx + ABYTES + i * 4096 + tid * 16, wb + srcB[i] + d);
            }
#pragma unroll
            for (int nf = 0; nf < 8; ++nf)
                c1[nf] = *(const short8*)(Acur + bB1 + nf * 2048);
#pragma unroll
            for (int mf = 0; mf < 10; ++mf)
                a1[mf] = *(const short8*)(Acur + aB1 + mf * 2048);

            __builtin_amdgcn_s_setprio(1);
#pragma unroll
            for (int mf = 0; mf < 10; ++mf) {
                if (wmbase + mf * 16 < rows) {
#pragma unroll
                    for (int nf = 0; nf < 8; ++nf)
                        acc[mf][nf] = __builtin_amdgcn_mfma_f32_16x16x32_bf16(
                            a0[mf], c0[nf], acc[mf][nf], 0, 0, 0);
                }
            }
#pragma unroll
            for (int mf = 0; mf < 10; ++mf) {
                if (wmbase + mf * 16 < rows) {
#pragma unroll
                    for (int nf = 0; nf < 8; ++nf)
                        acc[mf][nf] = __builtin_amdgcn_mfma_f32_16x16x32_bf16(
                            a1[mf], c1[nf], acc[mf][nf], 0, 0, 0);
                }
            }
            __builtin_amdgcn_s_setprio(0);
            __syncthreads();   // one barrier/step; drains vmcnt (stage t+1 landed)
        }

        // epilogue: tanh + W2 weighted row-sum
        float w2v[8], b1v[8];
#pragma unroll
        for (int nf = 0; nf < 8; ++nf) {
            int h = h0 + wn * 128 + nf * 16 + l15;
            w2v[nf] = w2[k * H_N + h];
            b1v[nf] = b1[k * H_N + h];
        }
#pragma unroll
        for (int mf = 0; mf < 10; ++mf) {
            float rs[4] = {0.f, 0.f, 0.f, 0.f};
#pragma unroll
            for (int nf = 0; nf < 8; ++nf) {
#pragma unroll
                for (int r = 0; r < 4; ++r)
                    rs[r] += fast_tanh(acc[mf][nf][r] + b1v[nf]) * w2v[nf];
            }
#pragma unroll
            for (int r = 0; r < 4; ++r) {
                float v = rs[r];
                v += __shfl_xor(v, 8);
                v += __shfl_xor(v, 4);
                v += __shfl_xor(v, 2);
                v += __shfl_xor(v, 1);
                if (l15 == 0) pll[wn * 320 + wmbase + mf * 16 + l4 * 4 + r] = v;
            }
        }
        __syncthreads();
#pragma unroll 2
        for (int i = tid; i < BM; i += 256) {
            int m = mt * BM + i;
            if (m < cnt) {
                u32 b = idxl[(size_t)k * B_N + m];
                llp[(size_t)nc * B_N + b] = pll[i] + pll[320 + i];
            }
        }
        __syncthreads();   // pll/ro safe for next item
    }
}

// ---------------- combine partials + b2 ----------------
__global__ void combine_kernel(const float* __restrict__ llp,
                               const int* __restrict__ cluster,
                               const float* __restrict__ b2,
                               float* __restrict__ out) {
    int b = blockIdx.x * 256 + threadIdx.x;
    float s = b2[cluster[b]];
#pragma unroll
    for (int nc = 0; nc < 8; ++nc) s += llp[(size_t)nc * B_N + b];
    out[b] = s;
}

extern "C" void kernel_launch(void* const* d_in, const int* in_sizes, int n_in,
                              void* d_out, int out_size, void* d_ws, size_t ws_size,
                              hipStream_t stream) {
    const float* x    = (const float*)d_in[0];
    const float* cent = (const float*)d_in[1];
    const float* W1   = (const float*)d_in[2];
    const float* b1   = (const float*)d_in[3];
    const float* W2   = (const float*)d_in[4];
    const float* b2   = (const float*)d_in[5];
    float* out = (float*)d_out;

    char* ws = (char*)d_ws;
    u16* xbf     = (u16*)(ws + 0);                 // 16 MB
    u16* w1t     = (u16*)(ws + 16777216);          // 32 MB
    u32* counts  = (u32*)(ws + 50331648);          // 8 strided u32 (1 KB pad)
    int* cluster = (int*)(ws + 50332672);          // 32 KB
    u32* idxl    = (u32*)(ws + 50365440);          // 256 KB
    float* llp   = (float*)(ws + 50627584);        // 256 KB

    (void)hipFuncSetAttribute((const void*)gemm_kernel,
                              hipFuncAttributeMaxDynamicSharedMemorySize, GEMM_LDS);

    hipLaunchKernelGGL(route_kernel, dim3(B_N / 4), dim3(256), 0, stream,
                       x, cent, xbf, cluster, counts);
    hipLaunchKernelGGL(scatter_kernel, dim3(32), dim3(256), 0, stream,
                       cluster, counts, idxl);
    hipLaunchKernelGGL(w1t_kernel, dim3(H_N / 64, D_N / 64, K_N), dim3(256), 0, stream,
                       W1, w1t);
    hipLaunchKernelGGL(gemm_kernel, dim3(NBLK), dim3(256), GEMM_LDS, stream,
                       xbf, w1t, b1, W2, idxl, counts, llp);
    hipLaunchKernelGGL(combine_kernel, dim3(B_N / 256), dim3(256), 0, stream,
                       llp, cluster, b2, out);
}

// Round 5
// 95.873 us; speedup vs baseline: 1.3129x; 1.3129x over previous
//
#include <hip/hip_runtime.h>
#include <hip/hip_bf16.h>
#include <stdint.h>

#define B_N 8192
#define D_N 1024
#define K_N 8
#define H_N 2048

#define BM 160
#define BN 128
#define BK 64
#define NBLK 512
// LDS map (bytes): 2 K-step buffers of (A 20480 + B 16384) = 36864:
//   buf0=0 buf1=36864 (end 73728)
//   ro=73728(640) pll=74368(1280)  total 75648 (2 blocks/CU: 2x75648 <= 163840)
#define ABYTES 20480
#define BUFSZ 36864
#define RO_OFF 73728
#define PLL_OFF 74368
#define GEMM_LDS 75648

typedef unsigned int u32;
typedef unsigned short u16;
typedef __attribute__((ext_vector_type(8))) short short8;
typedef __attribute__((ext_vector_type(4))) float float4v;

struct __align__(8) us4 { u16 x, y, z, w; };

__device__ __forceinline__ u16 f2bf(float f) {
    union { float f; u32 u; } v; v.f = f;
    u32 u = v.u;
    u32 r = (u + 0x7fffu + ((u >> 16) & 1u)) >> 16;
    return (u16)r;
}

__device__ __forceinline__ float fast_tanh(float x) {
    float t = __expf(2.0f * x);
    return 1.0f - 2.0f * __builtin_amdgcn_rcpf(t + 1.0f);
}

__device__ __forceinline__ void async_copy16(void* lds, const void* g) {
    __builtin_amdgcn_global_load_lds(
        (const __attribute__((address_space(1))) void*)g,
        (__attribute__((address_space(3))) void*)lds, 16, 0, 0);
}

// ---------------- routing: f64 argmin + x->bf16 (NO atomics) ----------------
__global__ void route_kernel(const float* __restrict__ x,
                             const float* __restrict__ cent,
                             u16* __restrict__ xbf,
                             int* __restrict__ cluster,
                             u32* __restrict__ counts) {
    int tid = threadIdx.x;
    if (blockIdx.x == 0 && tid < K_N) counts[tid * 32] = 0;  // zero strided counters
    int wave = tid >> 6, lane = tid & 63;
    int b = blockIdx.x * 4 + wave;
    const float* xr = x + (size_t)b * D_N;

    float4 xv[4];
#pragma unroll
    for (int i = 0; i < 4; ++i)
        xv[i] = *(const float4*)(xr + i * 256 + lane * 4);

#pragma unroll
    for (int i = 0; i < 4; ++i) {
        us4 o;
        o.x = f2bf(xv[i].x); o.y = f2bf(xv[i].y);
        o.z = f2bf(xv[i].z); o.w = f2bf(xv[i].w);
        *(us4*)(xbf + (size_t)b * D_N + i * 256 + lane * 4) = o;
    }

    double acc[K_N];
#pragma unroll
    for (int k = 0; k < K_N; ++k) {
        const float* cr = cent + k * D_N;
        double s = 0.0;
#pragma unroll
        for (int i = 0; i < 4; ++i) {
            float4 cv = *(const float4*)(cr + i * 256 + lane * 4);
            double d0 = (double)xv[i].x - (double)cv.x; s += d0 * d0;
            double d1 = (double)xv[i].y - (double)cv.y; s += d1 * d1;
            double d2 = (double)xv[i].z - (double)cv.z; s += d2 * d2;
            double d3 = (double)xv[i].w - (double)cv.w; s += d3 * d3;
        }
        acc[k] = s;
    }
#pragma unroll
    for (int k = 0; k < K_N; ++k) {
        double v = acc[k];
        for (int off = 32; off; off >>= 1) v += __shfl_down(v, off);
        acc[k] = v;
    }
    if (lane == 0) {
        int best = 0; double bv = acc[0];
#pragma unroll
        for (int k = 1; k < K_N; ++k)
            if (acc[k] < bv) { bv = acc[k]; best = k; }
        cluster[b] = best;
    }
}

// ---------------- parallel binning: 32 blocks, ballot-rank + block reserve ----------------
__global__ void scatter_kernel(const int* __restrict__ cluster,
                               u32* __restrict__ counts,
                               u32* __restrict__ idxl) {
    __shared__ u32 wcnt[4][K_N];
    __shared__ u32 gb[K_N];
    int tid = threadIdx.x;
    int b = blockIdx.x * 256 + tid;
    int lane = tid & 63, wid = tid >> 6;
    int cl = cluster[b];
    unsigned long long lower = (1ull << lane) - 1ull;
    u32 rank = 0;
#pragma unroll
    for (int k = 0; k < K_N; ++k) {
        unsigned long long mk = __ballot(cl == k);
        if (k == cl) rank = (u32)__popcll(mk & lower);
        if (lane == 0) wcnt[wid][k] = (u32)__popcll(mk);
    }
    __syncthreads();
    if (tid < K_N) {
        u32 tot = wcnt[0][tid] + wcnt[1][tid] + wcnt[2][tid] + wcnt[3][tid];
        gb[tid] = atomicAdd(&counts[tid * 32], tot);   // reserve range (order-free)
    }
    __syncthreads();
    u32 woff = 0;
    if (wid > 0) woff += wcnt[0][cl];
    if (wid > 1) woff += wcnt[1][cl];
    if (wid > 2) woff += wcnt[2][cl];
    idxl[(size_t)cl * B_N + gb[cl] + woff + rank] = (u32)b;
}

// ---------------- W1[k,d,h] f32 -> W1t[k,h,d] bf16 (vectorized) ----------------
__global__ void w1t_kernel(const float* __restrict__ w1, u16* __restrict__ w1t) {
    __shared__ float ts[64][65];
    int tid = threadIdx.x;
    int h0 = blockIdx.x * 64, d0 = blockIdx.y * 64, k = blockIdx.z;
    const float* src = w1 + ((size_t)k * D_N + d0) * H_N + h0;
#pragma unroll
    for (int i = 0; i < 4; ++i) {
        int q = i * 256 + tid;
        int r = q >> 4, c4 = (q & 15) * 4;          // d-row, h-col4
        float4 v = *(const float4*)(src + (size_t)r * H_N + c4);
        ts[c4 + 0][r] = v.x; ts[c4 + 1][r] = v.y;
        ts[c4 + 2][r] = v.z; ts[c4 + 3][r] = v.w;
    }
    __syncthreads();
    u16* dst = w1t + ((size_t)k * H_N + h0) * D_N + d0;
#pragma unroll
    for (int i = 0; i < 4; ++i) {
        int q = i * 256 + tid;
        int hr = q >> 4, d4 = (q & 15) * 4;         // h-row, d-col4
        us4 o;
        o.x = f2bf(ts[hr][d4 + 0]); o.y = f2bf(ts[hr][d4 + 1]);
        o.z = f2bf(ts[hr][d4 + 2]); o.w = f2bf(ts[hr][d4 + 3]);
        *(us4*)(dst + (size_t)hr * D_N + d4) = o;
    }
}

// ---------------- grouped fused GEMM: 160x128 tile, 4 waves, 2 BLOCKS/CU ----------------
// THE fix for the R0-R3 invariant (all ~50us at 1 block/CU): two co-resident
// INDEPENDENT blocks per CU (m97/m114 mechanism). When block A stalls at its
// vmcnt gate / barrier, block B's waves fill the SIMDs. 4 waves/block (2x2),
// wave tile 80x64 -> acc[5][4]=80 AGPR, ~190 regs total -> 2 waves/SIMD fits.
// LDS 75.6KB/block -> exactly 2/CU. Schedule: T3-minimum 2-phase w/ counted
// vmcnt(9); no lgkm pins (compiler emits counted lgkm for read->MFMA overlap).
// Item decode: XCD g (=blockIdx%8, 512%8==0 preserves it) handles nc in
// {2g,2g+1} -> per-XCD B set = 8 experts*2nc*256KB = 4MB = one XCD L2.
__global__ __launch_bounds__(256, 2) void gemm_kernel(
                            const u16* __restrict__ xbf,
                            const u16* __restrict__ w1t,
                            const float* __restrict__ b1,
                            const float* __restrict__ w2,
                            const u32* __restrict__ idxl,
                            const u32* __restrict__ counts,
                            float* __restrict__ llp) {
    extern __shared__ char lds[];
    int tid = threadIdx.x;
    int lane = tid & 63, w = tid >> 6;
    int wm = w >> 1, wn = w & 1;
    int wmbase = wm * 80;
    int l15 = lane & 15, l4 = lane >> 4;

    u32* ro = (u32*)(lds + RO_OFF);
    float* pll = (float*)(lds + PLL_OFF);

    // total work items (uniform across block): Sum ceil(cnt/160) * 16 nc-slices
    int ntiles = 0;
#pragma unroll
    for (int kk = 0; kk < K_N; ++kk)
        ntiles += ((int)counts[kk * 32] + BM - 1) / BM;
    int total = ntiles * 16;

    // per-lane fragment base offsets (chunk = (kk*4+l4) ^ (row&7); row&7 == l15&7)
    int swz = l15 & 7;
    u32 aB0 = (u32)((wmbase + l15) * 128 + (((0 + l4) ^ swz) << 4));
    u32 aB1 = (u32)((wmbase + l15) * 128 + (((4 + l4) ^ swz) << 4));
    u32 bB0 = (u32)(ABYTES + (wn * 64 + l15) * 128 + (((0 + l4) ^ swz) << 4));
    u32 bB1 = (u32)(ABYTES + (wn * 64 + l15) * 128 + (((4 + l4) ^ swz) << 4));

    const char* xb = (const char*)xbf;
    const char* wb = (const char*)w1t;

#define BAR() do { asm volatile("" ::: "memory"); __builtin_amdgcn_s_barrier(); \
                   asm volatile("" ::: "memory"); } while (0)

    for (int item = blockIdx.x; item < total; item += NBLK) {
        // decode: g = item&7 (XCD), ncl = (item>>3)&1, tile = item>>4
        int nc = ((item & 7) << 1) | ((item >> 3) & 1);
        int tile = item >> 4;
        int k = 0, mt = 0, nt = 0;
#pragma unroll
        for (int kk = 0; kk < K_N; ++kk) {
            int c = (int)counts[kk * 32];
            int t = (c + BM - 1) / BM;
            if (tile >= nt && tile < nt + t) { k = kk; mt = tile - nt; }
            nt += t;
        }
        int cnt = (int)counts[k * 32];
        int rows = cnt - mt * BM; if (rows > BM) rows = BM;
        int h0 = nc * BN;

        if (tid < BM) {
            int m = mt * BM + tid;
            int mm = m < cnt ? m : cnt - 1;
            ro[tid] = idxl[(size_t)k * B_N + mm] * (u32)(D_N * 2);
        }
        __syncthreads();

        // staging source offsets (pre-swizzled: linear LDS dest + swizzled read)
        u32 srcA[5], srcB[4];
#pragma unroll
        for (int i = 0; i < 5; ++i) {
            int c = i * 256 + tid; int r = c >> 3, j = c & 7;
            srcA[i] = ro[r] + ((u32)(j ^ (r & 7)) << 4);
        }
#pragma unroll
        for (int i = 0; i < 4; ++i) {
            int c = i * 256 + tid; int r = c >> 3, j = c & 7;
            srcB[i] = ((u32)(k * H_N + h0 + r) << 11) + ((u32)(j ^ (r & 7)) << 4);
        }

        float4v acc[5][4];
#pragma unroll
        for (int mf = 0; mf < 5; ++mf)
#pragma unroll
            for (int nf = 0; nf < 4; ++nf)
                acc[mf][nf] = (float4v){0.f, 0.f, 0.f, 0.f};

        // prologue: stage K-step 0 into buf 0 (9 DMA ops)
#pragma unroll
        for (int i = 0; i < 5; ++i)
            async_copy16(lds + i * 4096 + tid * 16, xb + srcA[i]);
#pragma unroll
        for (int i = 0; i < 4; ++i)
            async_copy16(lds + ABYTES + i * 4096 + tid * 16, wb + srcB[i]);

        for (int t = 0; t < 16; ++t) {
            const char* Acur = lds + (t & 1) * BUFSZ;
            char* Bnx = lds + ((t + 1) & 1) * BUFSZ;
            if (t < 15) {
                u32 d = (u32)((t + 1) << 7);
                // stage t+1 (9 ops) then wait for t's 9 (oldest) only: T4 counted
#pragma unroll
                for (int i = 0; i < 5; ++i)
                    async_copy16(Bnx + i * 4096 + tid * 16, xb + srcA[i] + d);
#pragma unroll
                for (int i = 0; i < 4; ++i)
                    async_copy16(Bnx + ABYTES + i * 4096 + tid * 16, wb + srcB[i] + d);
                asm volatile("s_waitcnt vmcnt(9)" ::: "memory");
            } else {
                asm volatile("s_waitcnt vmcnt(0)" ::: "memory");
            }
            BAR();   // buf t ready for all waves
#pragma unroll
            for (int kk = 0; kk < 2; ++kk) {
                short8 bC[4], a[5];
                u32 aB = kk ? aB1 : aB0, bB = kk ? bB1 : bB0;
#pragma unroll
                for (int nf = 0; nf < 4; ++nf)
                    bC[nf] = *(const short8*)(Acur + bB + nf * 2048);
#pragma unroll
                for (int mf = 0; mf < 5; ++mf)
                    a[mf] = *(const short8*)(Acur + aB + mf * 2048);
                __builtin_amdgcn_s_setprio(1);
#pragma unroll
                for (int mf = 0; mf < 5; ++mf) {
                    if (wmbase + mf * 16 < rows) {
#pragma unroll
                        for (int nf = 0; nf < 4; ++nf)
                            acc[mf][nf] = __builtin_amdgcn_mfma_f32_16x16x32_bf16(
                                a[mf], bC[nf], acc[mf][nf], 0, 0, 0);
                    }
                }
                __builtin_amdgcn_s_setprio(0);
            }
            BAR();   // reads of buf t done -> buf t free for stage at t+1 top
        }

        // epilogue: tanh + W2 weighted row-sum
        float w2v[4], b1v[4];
#pragma unroll
        for (int nf = 0; nf < 4; ++nf) {
            int h = h0 + wn * 64 + nf * 16 + l15;
            w2v[nf] = w2[k * H_N + h];
            b1v[nf] = b1[k * H_N + h];
        }
#pragma unroll
        for (int mf = 0; mf < 5; ++mf) {
            float rs[4] = {0.f, 0.f, 0.f, 0.f};
#pragma unroll
            for (int nf = 0; nf < 4; ++nf) {
#pragma unroll
                for (int r = 0; r < 4; ++r)
                    rs[r] += fast_tanh(acc[mf][nf][r] + b1v[nf]) * w2v[nf];
            }
#pragma unroll
            for (int r = 0; r < 4; ++r) {
                float v = rs[r];
                v += __shfl_xor(v, 8);
                v += __shfl_xor(v, 4);
                v += __shfl_xor(v, 2);
                v += __shfl_xor(v, 1);
                if (l15 == 0) pll[wn * 160 + wmbase + mf * 16 + l4 * 4 + r] = v;
            }
        }
        __syncthreads();
        if (tid < BM) {
            int m = mt * BM + tid;
            if (m < cnt) {
                u32 b = idxl[(size_t)k * B_N + m];
                llp[(size_t)nc * B_N + b] = pll[tid] + pll[160 + tid];
            }
        }
        __syncthreads();   // pll/ro safe for next item
    }
#undef BAR
}

// ---------------- combine partials + b2 (16 nc-slices) ----------------
__global__ void combine_kernel(const float* __restrict__ llp,
                               const int* __restrict__ cluster,
                               const float* __restrict__ b2,
                               float* __restrict__ out) {
    int b = blockIdx.x * 256 + threadIdx.x;
    float s = b2[cluster[b]];
#pragma unroll
    for (int nc = 0; nc < 16; ++nc) s += llp[(size_t)nc * B_N + b];
    out[b] = s;
}

extern "C" void kernel_launch(void* const* d_in, const int* in_sizes, int n_in,
                              void* d_out, int out_size, void* d_ws, size_t ws_size,
                              hipStream_t stream) {
    const float* x    = (const float*)d_in[0];
    const float* cent = (const float*)d_in[1];
    const float* W1   = (const float*)d_in[2];
    const float* b1   = (const float*)d_in[3];
    const float* W2   = (const float*)d_in[4];
    const float* b2   = (const float*)d_in[5];
    float* out = (float*)d_out;

    char* ws = (char*)d_ws;
    u16* xbf     = (u16*)(ws + 0);                 // 16 MB
    u16* w1t     = (u16*)(ws + 16777216);          // 32 MB
    u32* counts  = (u32*)(ws + 50331648);          // 8 strided u32 (1 KB pad)
    int* cluster = (int*)(ws + 50332672);          // 32 KB
    u32* idxl    = (u32*)(ws + 50365440);          // 256 KB
    float* llp   = (float*)(ws + 50627584);        // 512 KB (16 slices x 8192 f32)

    (void)hipFuncSetAttribute((const void*)gemm_kernel,
                              hipFuncAttributeMaxDynamicSharedMemorySize, GEMM_LDS);

    hipLaunchKernelGGL(route_kernel, dim3(B_N / 4), dim3(256), 0, stream,
                       x, cent, xbf, cluster, counts);
    hipLaunchKernelGGL(scatter_kernel, dim3(32), dim3(256), 0, stream,
                       cluster, counts, idxl);
    hipLaunchKernelGGL(w1t_kernel, dim3(H_N / 64, D_N / 64, K_N), dim3(256), 0, stream,
                       W1, w1t);
    hipLaunchKernelGGL(gemm_kernel, dim3(NBLK), dim3(256), GEMM_LDS, stream,
                       xbf, w1t, b1, W2, idxl, counts, llp);
    hipLaunchKernelGGL(combine_kernel, dim3(B_N / 256), dim3(256), 0, stream,
                       llp, cluster, b2, out);
}